// Round 6
// baseline (378.662 us; speedup 1.0000x reference)
//
#include <hip/hip_runtime.h>
#include <cmath>

#define NUM_LEVELS 16
#define TABLE_SIZE 524288
#define TMASK (TABLE_SIZE - 1)
#define HASH_PRIME 2654435761u
#define T_SAMPLES 192
#define BLOCK 256
#define PTS 64          // points per block; 4 waves split the 16 levels

typedef __bf16 bf16x8 __attribute__((ext_vector_type(8)));
typedef __bf16 bf16x4 __attribute__((ext_vector_type(4)));
typedef float f32x4 __attribute__((ext_vector_type(4)));

struct LvlParams {
    float s[NUM_LEVELS];
    int   res[NUM_LEVELS];
    int   hashed[NUM_LEVELS];
};

__device__ __forceinline__ float softplus10(float x) {
    float t = 10.0f * x;
    float e = __expf(-fabsf(t));
    return (fmaxf(t, 0.0f) + __logf(1.0f + e)) * 0.1f;
}

__device__ __forceinline__ void corner_idx(int cx, int cy, int res, int hashed,
                                           int& i00, int& i01, int& i10, int& i11) {
    if (hashed) {
        unsigned hy0 = (unsigned)cy * HASH_PRIME;
        unsigned hy1 = (unsigned)(cy + 1) * HASH_PRIME;
        i00 = (int)(((unsigned)cx ^ hy0) & TMASK);
        i01 = (int)(((unsigned)cx ^ hy1) & TMASK);
        i10 = (int)(((unsigned)(cx + 1) ^ hy0) & TMASK);
        i11 = (int)(((unsigned)(cx + 1) ^ hy1) & TMASK);
    } else {
        i00 = cy * res + cx; i10 = i00 + 1;
        i01 = i00 + res;     i11 = i01 + 1;
    }
}

__device__ __forceinline__ bf16x4 lerp4(f32x4 c00, f32x4 c01, f32x4 c10, f32x4 c11,
                                        float fx, float fy) {
    float w00 = (1.0f - fx) * (1.0f - fy), w01 = (1.0f - fx) * fy;
    float w10 = fx * (1.0f - fy),          w11 = fx * fy;
    f32x4 a = c00 * w00 + c01 * w01 + c10 * w10 + c11 * w11;
    bf16x4 r;
    r[0] = (__bf16)a.x; r[1] = (__bf16)a.y; r[2] = (__bf16)a.z; r[3] = (__bf16)a.w;
    return r;
}

// ---- prep: pack W0 into MFMA-B-fragment bf16 order + spread level params ----
// w0f flat f: j=f&7, lx=(f>>3)&15, q=(f>>7)&3, nt=(f>>9)&3, kc=f>>11
// k = kc*32+q*8+j ; n = nt*16+lx.
__global__ void prep(const float* __restrict__ W0, __bf16* __restrict__ w0f,
                     float* __restrict__ sArr, int* __restrict__ resArr,
                     int* __restrict__ hashArr, LvlParams lp) {
    const int t = threadIdx.x;
    if (t < NUM_LEVELS) {
        sArr[t] = lp.s[t]; resArr[t] = lp.res[t]; hashArr[t] = lp.hashed[t];
    }
    #pragma unroll
    for (int i = 0; i < 16; ++i) {
        int f = t * 16 + i;
        int j = f & 7, lx = (f >> 3) & 15, q = (f >> 7) & 3, nt = (f >> 9) & 3, kc = f >> 11;
        int k = kc * 32 + q * 8 + j;
        int n = nt * 16 + lx;
        w0f[f] = (__bf16)W0[k * 64 + n];
    }
}

// (256,8): 64-reg budget. R5 measured 40 VGPR at (256,5) -> slack. Sequential
// level consumption keeps encode live set ~45. Spill sentinel: WRITE_SIZE.
__launch_bounds__(BLOCK, 8)
__global__ void nerf_fused(const float* __restrict__ x,
                           const float* __restrict__ emb,
                           const __bf16* __restrict__ w0f,
                           const float* __restrict__ sArr,
                           const int* __restrict__ resArr,
                           const int* __restrict__ hashArr,
                           const float* __restrict__ b0,
                           const float* __restrict__ W1,
                           const float* __restrict__ b1,
                           float* __restrict__ out) {
    // Transposed feats tile: feT[level][point][dim], 16*64*4 bf16 = 8 KB.
    // Writes: b64 at word (l*128 + lane*2) -> bank 2*lane%32, conflict-free.
    // MFMA A-frag reads: two b64 at bank 2*lx, q-pairs 2-way aliased = free.
    __shared__ __align__(16) __bf16 feT[NUM_LEVELS * PTS * 4];

    const int tid  = threadIdx.x;
    const int lane = tid & 63, w = tid >> 6;   // lane = point-in-block

    // ---- ray setup for point = lane (duplicated across 4 waves, L1-hot) ----
    const int gp  = blockIdx.x * PTS + lane;
    const int ray = gp / T_SAMPLES;
    const int t   = gp - ray * T_SAMPLES;

    const float2 o  = *(const float2*)(x + (size_t)ray * (T_SAMPLES * 2));
    const float2 ep = *(const float2*)(x + (size_t)ray * (T_SAMPLES * 2) + (T_SAMPLES - 1) * 2);
    float rdx = ep.x - o.x, rdy = ep.y - o.y;
    float inv = 1.0f / sqrtf(rdx * rdx + rdy * rdy);
    rdx *= inv; rdy *= inv;
    const float z = (float)((double)t * (2.0 / 191.0));
    float px = fminf(fmaxf(o.x + rdx * z, -1.0f), 1.0f);
    float py = fminf(fmaxf(o.y + rdy * z, -1.0f), 1.0f);
    const float ux = (px + 1.0f) * 0.5f;
    const float uy = (py + 1.0f) * 0.5f;

    // this wave's levels: w, w+4, w+8, w+12  (exactly one expensive level each)
    const int l0 = w, l1 = w + 4, l2 = w + 8, l3 = w + 12;

    // ---- level l3 (12..15): issue 4 register gathers FIRST, consume LAST ----
    f32x4 c3v[4]; float fx3, fy3;
    {
        float s = sArr[l3];
        float posx = ux * s + 0.5f, posy = uy * s + 0.5f;
        float pfx = floorf(posx), pfy = floorf(posy);
        fx3 = posx - pfx; fy3 = posy - pfy;
        int cx = (int)pfx, cy = (int)pfy;
        int i00, i01, i10, i11;
        corner_idx(cx, cy, resArr[l3], hashArr[l3], i00, i01, i10, i11);
        const f32x4* tb = (const f32x4*)(emb + (size_t)l3 * (TABLE_SIZE * 4));
        c3v[0] = tb[i00]; c3v[1] = tb[i01]; c3v[2] = tb[i10]; c3v[3] = tb[i11];
    }

    // ---- level l2 (8..11): direct-indexed, issue then consume ----
    {
        float s = sArr[l2];
        float posx = ux * s + 0.5f, posy = uy * s + 0.5f;
        float pfx = floorf(posx), pfy = floorf(posy);
        float fx = posx - pfx, fy = posy - pfy;
        int cx = (int)pfx, cy = (int)pfy;
        int res = resArr[l2];
        int i00 = cy * res + cx, i10 = i00 + 1, i01 = i00 + res, i11 = i01 + 1;
        const f32x4* tb = (const f32x4*)(emb + (size_t)l2 * (TABLE_SIZE * 4));
        f32x4 a = tb[i00], b = tb[i01], c = tb[i10], d = tb[i11];
        *(bf16x4*)&feT[(l2 * PTS + lane) * 4] = lerp4(a, b, c, d, fx, fy);
    }

    // ---- level l1 (4..7): tiny, L1-resident ----
    {
        float s = sArr[l1];
        float posx = ux * s + 0.5f, posy = uy * s + 0.5f;
        float pfx = floorf(posx), pfy = floorf(posy);
        float fx = posx - pfx, fy = posy - pfy;
        int cx = (int)pfx, cy = (int)pfy;
        int res = resArr[l1];
        int i00 = cy * res + cx, i10 = i00 + 1, i01 = i00 + res, i11 = i01 + 1;
        const f32x4* tb = (const f32x4*)(emb + (size_t)l1 * (TABLE_SIZE * 4));
        f32x4 a = tb[i00], b = tb[i01], c = tb[i10], d = tb[i11];
        *(bf16x4*)&feT[(l1 * PTS + lane) * 4] = lerp4(a, b, c, d, fx, fy);
    }

    // ---- level l0 (0..3): tiny, L1-resident ----
    {
        float s = sArr[l0];
        float posx = ux * s + 0.5f, posy = uy * s + 0.5f;
        float pfx = floorf(posx), pfy = floorf(posy);
        float fx = posx - pfx, fy = posy - pfy;
        int cx = (int)pfx, cy = (int)pfy;
        int res = resArr[l0];
        int i00 = cy * res + cx, i10 = i00 + 1, i01 = i00 + res, i11 = i01 + 1;
        const f32x4* tb = (const f32x4*)(emb + (size_t)l0 * (TABLE_SIZE * 4));
        f32x4 a = tb[i00], b = tb[i01], c = tb[i10], d = tb[i11];
        *(bf16x4*)&feT[(l0 * PTS + lane) * 4] = lerp4(a, b, c, d, fx, fy);
    }

    // ---- consume l3 (its 4 misses have been in flight the whole time) ----
    *(bf16x4*)&feT[(l3 * PTS + lane) * 4] = lerp4(c3v[0], c3v[1], c3v[2], c3v[3], fx3, fy3);

    __syncthreads();   // all 4 waves' feature quarters visible

    // ---- MLP: wave w computes h for its own 16 points (M=16, N=64) ----
    const int lx = lane & 15, q = lane >> 4;
    const int p  = w * 16 + lx;

    f32x4 acc[4];
    #pragma unroll
    for (int nt = 0; nt < 4; ++nt) acc[nt] = (f32x4)(0.0f);

    #pragma unroll
    for (int kc = 0; kc < 2; ++kc) {
        // A-fragment: k = kc*32 + q*8 + j ; feats k = level*4 + dim
        const int la = kc * 8 + 2 * q;
        bf16x4 lo = *(const bf16x4*)&feT[(la * PTS + p) * 4];
        bf16x4 hi = *(const bf16x4*)&feT[((la + 1) * PTS + p) * 4];
        bf16x8 afr = __builtin_shufflevector(lo, hi, 0, 1, 2, 3, 4, 5, 6, 7);
        #pragma unroll
        for (int nt = 0; nt < 4; ++nt) {
            bf16x8 bfr = *(const bf16x8*)(w0f + (size_t)(((kc * 4 + nt) * 4 + q) * 16 + lx) * 8);
            acc[nt] = __builtin_amdgcn_mfma_f32_16x16x32_bf16(afr, bfr, acc[nt], 0, 0, 0);
        }
    }

    // ---- epilogue: softplus10 -> dot W1 -> reduce over 16 col-lanes ----
    float b0v[4], w1v[4];
    #pragma unroll
    for (int nt = 0; nt < 4; ++nt) {
        b0v[nt] = b0[nt * 16 + lx];
        w1v[nt] = W1[nt * 16 + lx];
    }
    const float b1v = b1[0];
    const float d0 = (float)(1.0 / 192.0);
    const float d1 = (float)(2.0 / 191.0);

    float part[4];
    #pragma unroll
    for (int r = 0; r < 4; ++r) {
        float pp = 0.0f;
        #pragma unroll
        for (int nt = 0; nt < 4; ++nt)
            pp += softplus10(acc[nt][r] + b0v[nt]) * w1v[nt];
        pp += __shfl_xor(pp, 1, 64);
        pp += __shfl_xor(pp, 2, 64);
        pp += __shfl_xor(pp, 4, 64);
        pp += __shfl_xor(pp, 8, 64);
        part[r] = pp;
    }
    if (lx == 0) {
        const int g0 = blockIdx.x * PTS + w * 16 + q * 4;   // multiple of 4
        const int tt = g0 % T_SAMPLES;
        f32x4 ov;
        ov.x = softplus10(part[0] + b1v) * (tt == 0 ? d0 : d1);
        ov.y = softplus10(part[1] + b1v) * d1;
        ov.z = softplus10(part[2] + b1v) * d1;
        ov.w = softplus10(part[3] + b1v) * d1;
        *(f32x4*)(out + g0) = ov;
    }
}

extern "C" void kernel_launch(void* const* d_in, const int* in_sizes, int n_in,
                              void* d_out, int out_size, void* d_ws, size_t ws_size,
                              hipStream_t stream) {
    const float* x   = (const float*)d_in[0];
    const float* emb = (const float*)d_in[1];
    const float* W0  = (const float*)d_in[2];
    const float* b0  = (const float*)d_in[3];
    const float* W1  = (const float*)d_in[4];
    const float* b1  = (const float*)d_in[5];
    float* out = (float*)d_out;

    // d_ws layout: [0,8192) w0f bf16; [8192,8256) sArr; [8256,8320) resArr;
    // [8320,8384) hashArr
    char* ws = (char*)d_ws;
    __bf16* w0f   = (__bf16*)ws;
    float* sArr   = (float*)(ws + 8192);
    int*   resArr = (int*)(ws + 8256);
    int*   hashArr= (int*)(ws + 8320);

    // Replicate numpy's level constants with the same host libm double ops.
    LvlParams lp;
    const double bb = std::exp((std::log(2048.0) - std::log(2.0)) / 15.0);
    for (int l = 0; l < NUM_LEVELS; ++l) {
        double sc = 2.0 * std::pow(bb, (double)l) - 1.0;
        int rr = (int)std::ceil(sc) + 1;
        lp.s[l] = (float)sc;
        lp.res[l] = rr;
        lp.hashed[l] = ((long long)rr * (long long)rr > (long long)TABLE_SIZE) ? 1 : 0;
    }

    prep<<<1, 256, 0, stream>>>(W0, w0f, sArr, resArr, hashArr, lp);

    const int nblk = out_size / PTS;   // 1572864/64 = 24576
    nerf_fused<<<nblk, BLOCK, 0, stream>>>(x, emb, w0f, sArr, resArr, hashArr,
                                           b0, W1, b1, out);
}

// Round 9
// 355.573 us; speedup vs baseline: 1.0649x; 1.0649x over previous
//
#include <hip/hip_runtime.h>
#include <cmath>
#include <algorithm>

#define NUM_LEVELS 16
#define TABLE_SIZE 524288
#define TMASK (TABLE_SIZE - 1)
#define HASH_PRIME 2654435761u
#define T_SAMPLES 192
#define BLOCK 256
#define PTS 64          // points per block; 4 waves split the 16 levels
#define CHUNK 4096      // entries per quantization chunk

typedef __bf16 bf16x8 __attribute__((ext_vector_type(8)));
typedef __bf16 bf16x4 __attribute__((ext_vector_type(4)));
typedef float f32x4 __attribute__((ext_vector_type(4)));
typedef short s16x4 __attribute__((ext_vector_type(4)));

struct LvlParams {
    float s[NUM_LEVELS];
    int   res[NUM_LEVELS];
    int   hashed[NUM_LEVELS];
    int   off[NUM_LEVELS];    // entry offset into compact i16 table (4096-aligned)
    int   used[NUM_LEVELS];   // entries actually referenced at this level
};

__device__ __forceinline__ float softplus10(float x) {
    float t = 10.0f * x;
    float e = __expf(-fabsf(t));
    return (fmaxf(t, 0.0f) + __logf(1.0f + e)) * 0.1f;
}

__device__ __forceinline__ void corner_idx(int cx, int cy, int res, int hashed,
                                           int& i00, int& i01, int& i10, int& i11) {
    if (hashed) {
        unsigned hy0 = (unsigned)cy * HASH_PRIME;
        unsigned hy1 = (unsigned)(cy + 1) * HASH_PRIME;
        i00 = (int)(((unsigned)cx ^ hy0) & TMASK);
        i01 = (int)(((unsigned)cx ^ hy1) & TMASK);
        i10 = (int)(((unsigned)(cx + 1) ^ hy0) & TMASK);
        i11 = (int)(((unsigned)(cx + 1) ^ hy1) & TMASK);
    } else {
        // NOTE: reference has NO bounds clamp; at u=1 on integer-scale levels
        // idx runs past res*res-1 into the table tail. used[] must cover it.
        i00 = cy * res + cx; i10 = i00 + 1;
        i01 = i00 + res;     i11 = i01 + 1;
    }
}

__device__ __forceinline__ bf16x4 lerp4(f32x4 c00, f32x4 c01, f32x4 c10, f32x4 c11,
                                        float fx, float fy) {
    float w00 = (1.0f - fx) * (1.0f - fy), w01 = (1.0f - fx) * fy;
    float w10 = fx * (1.0f - fy),          w11 = fx * fy;
    f32x4 a = c00 * w00 + c01 * w01 + c10 * w10 + c11 * w11;
    bf16x4 r;
    r[0] = (__bf16)a.x; r[1] = (__bf16)a.y; r[2] = (__bf16)a.z; r[3] = (__bf16)a.w;
    return r;
}

// ---- prep: pack W0 into MFMA-B-fragment bf16 order + spread level params ----
__global__ void prep(const float* __restrict__ W0, __bf16* __restrict__ w0f,
                     float* __restrict__ sArr, int* __restrict__ resArr,
                     int* __restrict__ hashArr, int* __restrict__ offArr,
                     int* __restrict__ usedArr, LvlParams lp) {
    const int t = threadIdx.x;
    if (t < NUM_LEVELS) {
        sArr[t] = lp.s[t]; resArr[t] = lp.res[t]; hashArr[t] = lp.hashed[t];
        offArr[t] = lp.off[t]; usedArr[t] = lp.used[t];
    }
    #pragma unroll
    for (int i = 0; i < 16; ++i) {
        int f = t * 16 + i;
        int j = f & 7, lx = (f >> 3) & 15, q = (f >> 7) & 3, nt = (f >> 9) & 3, kc = f >> 11;
        int k = kc * 32 + q * 8 + j;
        int n = nt * 16 + lx;
        w0f[f] = (__bf16)W0[k * 64 + n];
    }
}

// ---- prep_tables: one-pass per-chunk absmax -> i16 quantize of used entries ----
__global__ void prep_tables(const float* __restrict__ emb, short* __restrict__ embq,
                            float* __restrict__ scaleArr,
                            const int* __restrict__ offArr, const int* __restrict__ usedArr) {
    __shared__ float red[256];
    const int l    = blockIdx.y;
    const int used = usedArr[l];
    const int base = blockIdx.x * CHUNK;          // entry base within level
    if (base >= used) return;                     // uniform early-out (pre-barrier)
    const int t = threadIdx.x;
    const float* src = emb + ((size_t)l * TABLE_SIZE + base) * 4;

    f32x4 v[16];
    float m = 0.0f;
    #pragma unroll
    for (int i = 0; i < 16; ++i) {
        int e = t + 256 * i;
        if (base + e < used) {
            v[i] = *(const f32x4*)(src + (size_t)e * 4);
            m = fmaxf(m, fmaxf(fmaxf(fabsf(v[i].x), fabsf(v[i].y)),
                               fmaxf(fabsf(v[i].z), fabsf(v[i].w))));
        } else v[i] = (f32x4)(0.0f);
    }
    red[t] = m;
    __syncthreads();
    for (int s = 128; s > 0; s >>= 1) {
        if (t < s) red[t] = fmaxf(red[t], red[t + s]);
        __syncthreads();
    }
    const float mx  = red[0];
    const float inv = (mx > 0.0f) ? (32767.0f / mx) : 0.0f;
    const int chunkIdx = (offArr[l] >> 12) + blockIdx.x;
    if (t == 0) scaleArr[chunkIdx] = (mx > 0.0f) ? (mx / 32767.0f) : 0.0f;

    short* dst = embq + (size_t)(offArr[l] + base) * 4;
    #pragma unroll
    for (int i = 0; i < 16; ++i) {
        int e = t + 256 * i;
        if (base + e < used) {
            s16x4 q;
            q[0] = (short)__float2int_rn(v[i].x * inv);
            q[1] = (short)__float2int_rn(v[i].y * inv);
            q[2] = (short)__float2int_rn(v[i].z * inv);
            q[3] = (short)__float2int_rn(v[i].w * inv);
            *(s16x4*)(dst + (size_t)e * 4) = q;
        }
    }
}

// QT=true: gathers from compact i16 tables (half the fp32 footprint).
template<bool QT>
__launch_bounds__(BLOCK, 8)
__global__ void nerf_fused(const float* __restrict__ x,
                           const float* __restrict__ emb,
                           const short* __restrict__ embq,
                           const float* __restrict__ scaleArr,
                           const __bf16* __restrict__ w0f,
                           const float* __restrict__ sArr,
                           const int* __restrict__ resArr,
                           const int* __restrict__ hashArr,
                           const int* __restrict__ offArr,
                           const float* __restrict__ b0,
                           const float* __restrict__ W1,
                           const float* __restrict__ b1,
                           float* __restrict__ out) {
    // Transposed feats tile: feT[level][point][dim], 16*64*4 bf16 = 8 KB.
    __shared__ __align__(16) __bf16 feT[NUM_LEVELS * PTS * 4];

    const int tid  = threadIdx.x;
    const int lane = tid & 63, w = tid >> 6;   // lane = point-in-block

    // ---- ray setup for point = lane (duplicated across 4 waves, L1-hot) ----
    const int gp  = blockIdx.x * PTS + lane;
    const int ray = gp / T_SAMPLES;
    const int t   = gp - ray * T_SAMPLES;

    const float2 o  = *(const float2*)(x + (size_t)ray * (T_SAMPLES * 2));
    const float2 ep = *(const float2*)(x + (size_t)ray * (T_SAMPLES * 2) + (T_SAMPLES - 1) * 2);
    float rdx = ep.x - o.x, rdy = ep.y - o.y;
    float inv = 1.0f / sqrtf(rdx * rdx + rdy * rdy);
    rdx *= inv; rdy *= inv;
    const float z = (float)((double)t * (2.0 / 191.0));
    float px = fminf(fmaxf(o.x + rdx * z, -1.0f), 1.0f);
    float py = fminf(fmaxf(o.y + rdy * z, -1.0f), 1.0f);
    const float ux = (px + 1.0f) * 0.5f;
    const float uy = (py + 1.0f) * 0.5f;

    // this wave's levels: w, w+4, w+8, w+12  (exactly one expensive level each)
    const int l3 = w + 12;

    // ---- level l3 (12..15): issue 4 gathers FIRST, consume LAST ----
    f32x4 c3v[4]; float fx3, fy3;
    {
        float s = sArr[l3];
        float posx = ux * s + 0.5f, posy = uy * s + 0.5f;
        float pfx = floorf(posx), pfy = floorf(posy);
        fx3 = posx - pfx; fy3 = posy - pfy;
        int cx = (int)pfx, cy = (int)pfy;
        int i00, i01, i10, i11;
        corner_idx(cx, cy, resArr[l3], hashArr[l3], i00, i01, i10, i11);
        if (QT) {
            const s16x4* tb = (const s16x4*)embq + offArr[l3];
            const int cb = offArr[l3] >> 12;
            s16x4 r0 = tb[i00], r1 = tb[i01], r2 = tb[i10], r3 = tb[i11];
            c3v[0] = __builtin_convertvector(r0, f32x4) * scaleArr[cb + (i00 >> 12)];
            c3v[1] = __builtin_convertvector(r1, f32x4) * scaleArr[cb + (i01 >> 12)];
            c3v[2] = __builtin_convertvector(r2, f32x4) * scaleArr[cb + (i10 >> 12)];
            c3v[3] = __builtin_convertvector(r3, f32x4) * scaleArr[cb + (i11 >> 12)];
        } else {
            const f32x4* tb = (const f32x4*)(emb + (size_t)l3 * (TABLE_SIZE * 4));
            c3v[0] = tb[i00]; c3v[1] = tb[i01]; c3v[2] = tb[i10]; c3v[3] = tb[i11];
        }
    }

    // ---- levels l2, l1, l0: issue, lerp, write straight to LDS ----
    #pragma unroll
    for (int li = 0; li < 3; ++li) {
        const int l = w + li * 4;              // uniform per wave
        float s = sArr[l];
        float posx = ux * s + 0.5f, posy = uy * s + 0.5f;
        float pfx = floorf(posx), pfy = floorf(posy);
        float fx = posx - pfx, fy = posy - pfy;
        int cx = (int)pfx, cy = (int)pfy;
        int res = resArr[l];
        int i00 = cy * res + cx, i10 = i00 + 1, i01 = i00 + res, i11 = i01 + 1;
        f32x4 a, b, c, d;
        if (QT) {
            const s16x4* tb = (const s16x4*)embq + offArr[l];
            const int cb = offArr[l] >> 12;
            s16x4 r0 = tb[i00], r1 = tb[i01], r2 = tb[i10], r3 = tb[i11];
            a = __builtin_convertvector(r0, f32x4) * scaleArr[cb + (i00 >> 12)];
            b = __builtin_convertvector(r1, f32x4) * scaleArr[cb + (i01 >> 12)];
            c = __builtin_convertvector(r2, f32x4) * scaleArr[cb + (i10 >> 12)];
            d = __builtin_convertvector(r3, f32x4) * scaleArr[cb + (i11 >> 12)];
        } else {
            const f32x4* tb = (const f32x4*)(emb + (size_t)l * (TABLE_SIZE * 4));
            a = tb[i00]; b = tb[i01]; c = tb[i10]; d = tb[i11];
        }
        *(bf16x4*)&feT[(l * PTS + lane) * 4] = lerp4(a, b, c, d, fx, fy);
    }

    // ---- consume l3 (its 4 misses have been in flight the whole time) ----
    *(bf16x4*)&feT[(l3 * PTS + lane) * 4] = lerp4(c3v[0], c3v[1], c3v[2], c3v[3], fx3, fy3);

    __syncthreads();   // all 4 waves' feature quarters visible

    // ---- MLP: wave w computes h for its own 16 points (M=16, N=64) ----
    const int lx = lane & 15, q = lane >> 4;
    const int p  = w * 16 + lx;

    f32x4 acc[4];
    #pragma unroll
    for (int nt = 0; nt < 4; ++nt) acc[nt] = (f32x4)(0.0f);

    #pragma unroll
    for (int kc = 0; kc < 2; ++kc) {
        // A-fragment: k = kc*32 + q*8 + j ; feats k = level*4 + dim
        const int la = kc * 8 + 2 * q;
        bf16x4 lo = *(const bf16x4*)&feT[(la * PTS + p) * 4];
        bf16x4 hi = *(const bf16x4*)&feT[((la + 1) * PTS + p) * 4];
        bf16x8 afr = __builtin_shufflevector(lo, hi, 0, 1, 2, 3, 4, 5, 6, 7);
        #pragma unroll
        for (int nt = 0; nt < 4; ++nt) {
            bf16x8 bfr = *(const bf16x8*)(w0f + (size_t)(((kc * 4 + nt) * 4 + q) * 16 + lx) * 8);
            acc[nt] = __builtin_amdgcn_mfma_f32_16x16x32_bf16(afr, bfr, acc[nt], 0, 0, 0);
        }
    }

    // ---- epilogue: softplus10 -> dot W1 -> reduce over 16 col-lanes ----
    float b0v[4], w1v[4];
    #pragma unroll
    for (int nt = 0; nt < 4; ++nt) {
        b0v[nt] = b0[nt * 16 + lx];
        w1v[nt] = W1[nt * 16 + lx];
    }
    const float b1v = b1[0];
    const float d0 = (float)(1.0 / 192.0);
    const float d1 = (float)(2.0 / 191.0);

    float part[4];
    #pragma unroll
    for (int r = 0; r < 4; ++r) {
        float pp = 0.0f;
        #pragma unroll
        for (int nt = 0; nt < 4; ++nt)
            pp += softplus10(acc[nt][r] + b0v[nt]) * w1v[nt];
        pp += __shfl_xor(pp, 1, 64);
        pp += __shfl_xor(pp, 2, 64);
        pp += __shfl_xor(pp, 4, 64);
        pp += __shfl_xor(pp, 8, 64);
        part[r] = pp;
    }
    if (lx == 0) {
        const int g0 = blockIdx.x * PTS + w * 16 + q * 4;   // multiple of 4
        const int tt = g0 % T_SAMPLES;
        f32x4 ov;
        ov.x = softplus10(part[0] + b1v) * (tt == 0 ? d0 : d1);
        ov.y = softplus10(part[1] + b1v) * d1;
        ov.z = softplus10(part[2] + b1v) * d1;
        ov.w = softplus10(part[3] + b1v) * d1;
        *(f32x4*)(out + g0) = ov;
    }
}

extern "C" void kernel_launch(void* const* d_in, const int* in_sizes, int n_in,
                              void* d_out, int out_size, void* d_ws, size_t ws_size,
                              hipStream_t stream) {
    const float* x   = (const float*)d_in[0];
    const float* emb = (const float*)d_in[1];
    const float* W0  = (const float*)d_in[2];
    const float* b0  = (const float*)d_in[3];
    const float* W1  = (const float*)d_in[4];
    const float* b1  = (const float*)d_in[5];
    float* out = (float*)d_out;

    // ws layout: [0,8192) w0f; [8192,8512) param arrays; [8704,16384) scaleArr
    // (up to 1920 chunks); embq at 16384.
    char* ws = (char*)d_ws;
    __bf16* w0f    = (__bf16*)ws;
    float*  sArr   = (float*)(ws + 8192);
    int*    resArr = (int*)(ws + 8256);
    int*    hashArr= (int*)(ws + 8320);
    int*    offArr = (int*)(ws + 8384);
    int*    usedArr= (int*)(ws + 8448);
    float*  scaleArr = (float*)(ws + 8704);
    short*  embq   = (short*)(ws + 16384);

    // Replicate numpy's level constants with the same host libm double ops.
    LvlParams lp;
    const double bb = std::exp((std::log(2048.0) - std::log(2.0)) / 15.0);
    int off = 0, maxUsed = 0;
    for (int l = 0; l < NUM_LEVELS; ++l) {
        double sc = 2.0 * std::pow(bb, (double)l) - 1.0;
        int rr = (int)std::ceil(sc) + 1;
        lp.s[l] = (float)sc;
        lp.res[l] = rr;
        lp.hashed[l] = ((long long)rr * (long long)rr > (long long)TABLE_SIZE) ? 1 : 0;
        int used;
        if (lp.hashed[l]) {
            used = TABLE_SIZE;
        } else {
            // Reference does NOT clamp corners: max idx = cmax*res + cmax where
            // cmax = floor(s+0.5)+1 (reachable at u=1). Cover it, + margin for
            // float(s) vs double(s) coordinate rounding.
            long long cmax = (long long)std::floor(sc + 0.5) + 1;
            long long u = cmax * (long long)rr + cmax + 1 + (rr + 2);
            used = (int)std::min((long long)TABLE_SIZE, u);
        }
        lp.off[l]  = off;
        lp.used[l] = used;
        off += (used + CHUNK - 1) & ~(CHUNK - 1);   // keep chunks level-aligned
        if (used > maxUsed) maxUsed = used;
    }
    const size_t need = 16384 + (size_t)off * 4 * sizeof(short);   // ~16.5 MB
    const bool useQ = ws_size >= need;

    prep<<<1, 256, 0, stream>>>(W0, w0f, sArr, resArr, hashArr, offArr, usedArr, lp);

    const int nblk = out_size / PTS;   // 1572864/64 = 24576
    if (useQ) {
        dim3 pg((maxUsed + CHUNK - 1) / CHUNK, NUM_LEVELS);
        prep_tables<<<pg, 256, 0, stream>>>(emb, embq, scaleArr, offArr, usedArr);
        nerf_fused<true><<<nblk, BLOCK, 0, stream>>>(x, emb, embq, scaleArr, w0f,
                                                     sArr, resArr, hashArr, offArr,
                                                     b0, W1, b1, out);
    } else {
        nerf_fused<false><<<nblk, BLOCK, 0, stream>>>(x, emb, embq, scaleArr, w0f,
                                                      sArr, resArr, hashArr, offArr,
                                                      b0, W1, b1, out);
    }
}